// Round 13
// baseline (23.567 us; speedup 1.0000x reference)
//
#include <hip/hip_runtime.h>
#include <math.h>

#define PI_F 3.14159265358979323846f

typedef float    f32x4 __attribute__((ext_vector_type(4)));
typedef _Float16 h2    __attribute__((ext_vector_type(2)));

#if __has_builtin(__builtin_elementwise_fma)
#define FMA2(a, b, c) __builtin_elementwise_fma((a), (b), (c))
#else
#define FMA2(a, b, c) ((a) * (b) + (c))
#endif

// v_cvt_pkrtz_f16_f32: packs a->low(elt0), b->high(elt1)
__device__ __forceinline__ h2 pkrtz(float a, float b) {
    return __builtin_bit_cast(h2, __builtin_amdgcn_cvt_pkrtz(a, b));
}

// ---- cross-lane primitives ----
// ds_swizzle BitMode: and=offset[4:0], or=offset[9:5], xor=offset[14:10]
template <int PAT>
__device__ __forceinline__ h2 swzh(h2 x) {
    return __builtin_bit_cast(h2, __builtin_amdgcn_ds_swizzle(__builtin_bit_cast(int, x), PAT));
}
// Broadcast qubit q's (c,s) to ALL lanes: src_lane = q (same in both 32-halves,
// lanes q and 32+q hold identical values). Pattern: and=0, or=q, xor=0.
#define BCASTALL_PAT(q) ((q) << 5)
// Butterfly xor within 32-half (ISA-doc patterns): (mask<<10)|0x1F
#define SWZ_XOR4  0x101F
#define SWZ_XOR16 0x401F

template <int CTRL>
__device__ __forceinline__ h2 dpph(h2 x) {
    int i = __builtin_bit_cast(int, x);
    return __builtin_bit_cast(h2, __builtin_amdgcn_update_dpp(i, i, CTRL, 0xF, 0xF, false));
}
#define DPP_XOR1 0xB1   // quad_perm [1,0,3,2]
#define DPP_XOR2 0x4E   // quad_perm [2,3,0,1]
#define DPP_XOR8 0x128  // row_ror:8 == lane^8 within 16-row

__device__ __forceinline__ h2 xor32h(h2 x) {
    return __builtin_bit_cast(h2, __shfl_xor(__builtin_bit_cast(int, x), 32, 64));
}

// boring half-swap: (lo,hi) -> (hi,lo)
__device__ __forceinline__ h2 hswap(h2 a) {
    return __builtin_shufflevector(a, a, 1, 0);
}
__device__ __forceinline__ h2 splat_lo(h2 a) { h2 r = { a[0], a[0] }; return r; }
__device__ __forceinline__ h2 splat_hi(h2 a) { h2 r = { a[1], a[1] }; return r; }

__global__ __launch_bounds__(256) void qenc_kernel(
    const float* __restrict__ pf,     // [B, 8]
    const float* __restrict__ theta,  // [2, 8]
    const float* __restrict__ scale,  // [8]
    float* __restrict__ out,          // [B, 256]
    int B)
{
    const int lane = threadIdx.x & 63;
    const int wid  = threadIdx.x >> 6;
    const int b    = blockIdx.x * 4 + wid;    // one batch per wave
    const int sub  = lane & 7;                // qubit this lane computes angles for

    // ---- angles (8-way redundant across the wave; uniform control flow) ----
    float x  = pf[(size_t)b * 8 + sub];
    float e  = __expf(2.f * x);
    float th = 1.f - 2.f / (e + 1.f);             // tanh(x)
    float b2 = th * (0.5f * PI_F) * scale[sub];
    float h0a = b2 + 0.5f * theta[sub];
    float h1a = b2 + 0.5f * theta[8 + sub];
    h2 cs0 = pkrtz(__cosf(h0a), __sinf(h0a));     // layer-0 (c,s)
    h2 csl = pkrtz(__cosf(h1a), __sinf(h1a));     // layer-1 (c,s)

    // ---- broadcast all 8 qubits' packed (c,s), both layers (16 swizzles) ----
    h2 k0 = swzh<BCASTALL_PAT(0)>(cs0), k1 = swzh<BCASTALL_PAT(1)>(cs0);
    h2 k2 = swzh<BCASTALL_PAT(2)>(cs0), k3 = swzh<BCASTALL_PAT(3)>(cs0);
    h2 k4 = swzh<BCASTALL_PAT(4)>(cs0), k5 = swzh<BCASTALL_PAT(5)>(cs0);
    h2 k6 = swzh<BCASTALL_PAT(6)>(cs0), k7 = swzh<BCASTALL_PAT(7)>(cs0);
    h2 q0 = swzh<BCASTALL_PAT(0)>(csl), q1 = swzh<BCASTALL_PAT(1)>(csl);
    h2 q2 = swzh<BCASTALL_PAT(2)>(csl), q3 = swzh<BCASTALL_PAT(3)>(csl);
    h2 q4 = swzh<BCASTALL_PAT(4)>(csl), q5 = swzh<BCASTALL_PAT(5)>(csl);
    h2 q6 = swzh<BCASTALL_PAT(6)>(csl), q7 = swzh<BCASTALL_PAT(7)>(csl);

    // ---- layer 0 tensor product ----
    // state idx = lane*4 + e : idx bit0,1 = e bits; idx bits 2..7 = lane bits 0..5.
    // G = prod_{q=2..7} f_q(lane bit q-2), f32 for accuracy.
    float G;
    G  = (lane & 1)  ? (float)k2[1] : (float)k2[0];
    G *= (lane & 2)  ? (float)k3[1] : (float)k3[0];
    G *= (lane & 4)  ? (float)k4[1] : (float)k4[0];
    G *= (lane & 8)  ? (float)k5[1] : (float)k5[0];
    G *= (lane & 16) ? (float)k6[1] : (float)k6[0];
    G *= (lane & 32) ? (float)k7[1] : (float)k7[0];

    // CZ#1 decomposition for idx = lane*4 + e:
    //  per-lane: pairs (2,3)..(6,7) -> SL = (-1)^popc(lane & lane>>1 & 0x1F)
    //  pair (1,2): hits e>=2 when lane bit0 -> lam on P1
    //  pair (0,1): hits e==3 always      -> extra (-1) on P1[1]
    float SL  = (__popc(lane & (lane >> 1) & 0x1F) & 1) ? -1.f : 1.f;
    float lam = (lane & 1) ? -1.f : 1.f;

    // P0 = amps(e0,e1) = G*SL * c1 * (c0, s0)
    // P1 = amps(e2,e3) = G*SL * s1*lam * (c0, -s0)
    float Gs = G * SL;
    float gc = Gs * (float)k1[0];
    float gs = Gs * (float)k1[1] * lam;
    h2 P0 = pkrtz(gc * (float)k0[0],  gc * (float)k0[1]);
    h2 P1 = pkrtz(gs * (float)k0[0], -gs * (float)k0[1]);

    // ---- layer 1: 6 cross-lane gates, then q1 (reg pair), then q0 (in-pack) ----
#define XGATE(EXCH, BIT, cs)                                          \
    do {                                                              \
        h2 c2 = splat_lo(cs), s2 = splat_hi(cs);                      \
        h2 se = (lane & (BIT)) ? s2 : -s2;                            \
        h2 t0 = EXCH(P0), t1 = EXCH(P1);                              \
        P0 = FMA2(c2, P0, se * t0);                                   \
        P1 = FMA2(c2, P1, se * t1);                                   \
    } while (0)

    XGATE(dpph<DPP_XOR1>,  1,  q2);   // qubit 2 <-> lane bit 0
    XGATE(dpph<DPP_XOR2>,  2,  q3);   // qubit 3 <-> lane bit 1
    XGATE(swzh<SWZ_XOR4>,  4,  q4);   // qubit 4 <-> lane bit 2
    XGATE(dpph<DPP_XOR8>,  8,  q5);   // qubit 5 <-> lane bit 3
    XGATE(swzh<SWZ_XOR16>, 16, q6);   // qubit 6 <-> lane bit 4
    XGATE(xor32h,          32, q7);   // qubit 7 <-> lane bit 5

    {   // qubit 1: butterfly between P0 and P1
        h2 c2 = splat_lo(q1), s2 = splat_hi(q1);
        h2 a = P0, bb = P1;
        P0 = FMA2(c2, a, -(s2 * bb));
        P1 = FMA2(c2, bb, s2 * a);
    }
    {   // qubit 0: within-pack butterfly (R12-proven)
        h2 c2 = splat_lo(q0);
        _Float16 sh = q0[1];
        h2 sm = { (_Float16)(-sh), sh };      // (-s, s)
        P0 = FMA2(c2, P0, sm * hswap(P0));
        P1 = FMA2(c2, P1, sm * hswap(P1));
    }

    // ---- CZ#2: exact +-1 multiplies, same decomposition as CZ#1 ----
    float SLl = SL * lam;
    h2 z0 = { (_Float16)SL,  (_Float16)SL };
    h2 z1 = { (_Float16)SLl, (_Float16)(-SLl) };
    P0 = P0 * z0;
    P1 = P1 * z1;
    // (no normalization: gates orthogonal, ||state|| = 1 within f16 rounding << bf16 tol)

    // ---- naturally coalesced store: lane*16B, 1 KB contiguous per wave ----
    f32x4 o = { (float)P0[0], (float)P0[1], (float)P1[0], (float)P1[1] };
    __builtin_nontemporal_store(o,
        reinterpret_cast<f32x4*>(out + (size_t)b * 256 + lane * 4));
}

extern "C" void kernel_launch(void* const* d_in, const int* in_sizes, int n_in,
                              void* d_out, int out_size, void* d_ws, size_t ws_size,
                              hipStream_t stream) {
    const float* pf    = (const float*)d_in[0];  // [B, 8]
    const float* theta = (const float*)d_in[1];  // [2, 8]
    const float* scale = (const float*)d_in[2];  // [8]
    float* out = (float*)d_out;

    int B = in_sizes[0] / 8;              // 65536
    // one batch per wave, 4 waves/block -> 16384 blocks; no LDS storage,
    // ~40 VGPR -> 32 waves/CU, fine-grained generational pipelining
    int grid = B / 4;
    qenc_kernel<<<grid, 256, 0, stream>>>(pf, theta, scale, out, B);
}

// Round 14
// 17.557 us; speedup vs baseline: 1.3423x; 1.3423x over previous
//
#include <hip/hip_runtime.h>
#include <math.h>

#define PI_F 3.14159265358979323846f

typedef float    f32x4 __attribute__((ext_vector_type(4)));
typedef _Float16 h2    __attribute__((ext_vector_type(2)));

#if __has_builtin(__builtin_elementwise_fma)
#define FMA2(a, b, c) __builtin_elementwise_fma((a), (b), (c))
#else
#define FMA2(a, b, c) ((a) * (b) + (c))
#endif

// v_cvt_pkrtz_f16_f32: packs a->low(elt0), b->high(elt1)
__device__ __forceinline__ h2 pkrtz(float a, float b) {
    return __builtin_bit_cast(h2, __builtin_amdgcn_cvt_pkrtz(a, b));
}

// ---- cross-lane primitives ----
// ds_swizzle BitMode: and=offset[4:0], or=offset[9:5], xor=offset[14:10]
template <int PAT>
__device__ __forceinline__ h2 swzh(h2 x) {
    return __builtin_bit_cast(h2, __builtin_amdgcn_ds_swizzle(__builtin_bit_cast(int, x), PAT));
}
// Broadcast qubit q's (c,s) within each 8-lane group: sub on lane bits 0-2,
// group on lane bits 3,4 (bit 5 auto-preserved): and=0x18, or=q  (R1/R2-proven)
#define BCAST_PAT(q) (((q) << 5) | 0x18)
// Butterfly xor4 within 32-half (ISA-doc pattern)
#define SWZ_XOR4 0x101F

template <int CTRL>
__device__ __forceinline__ h2 dpph(h2 x) {
    int i = __builtin_bit_cast(int, x);
    return __builtin_bit_cast(h2, __builtin_amdgcn_update_dpp(i, i, CTRL, 0xF, 0xF, false));
}
#define DPP_XOR1 0xB1   // quad_perm [1,0,3,2]
#define DPP_XOR2 0x4E   // quad_perm [2,3,0,1]

// boring half-swap: (lo,hi) -> (hi,lo)
__device__ __forceinline__ h2 hswap(h2 a) {
    return __builtin_shufflevector(a, a, 1, 0);
}
__device__ __forceinline__ h2 splat_lo(h2 a) { h2 r = { a[0], a[0] }; return r; }
__device__ __forceinline__ h2 splat_hi(h2 a) { h2 r = { a[1], a[1] }; return r; }

__global__ __launch_bounds__(256) void qenc_kernel(
    const float* __restrict__ pf,     // [B, 8]
    const float* __restrict__ theta,  // [2, 8]
    const float* __restrict__ scale,  // [8]
    float* __restrict__ out,          // [B, 256]
    int B)
{
    const int lane = threadIdx.x & 63;
    const int wid  = threadIdx.x >> 6;
    const int sub  = lane & 7;        // qubit-owner index AND idx bits 2..4
    const int g    = lane >> 3;       // batch within wave (8 per wave)

    const int grp   = blockIdx.x * 4 + wid;
    const int bwave = grp * 8;
    const int b     = bwave + g;

    // ---- angles: this lane owns qubit `sub` of batch `b`, both layers ----
    float x  = pf[(size_t)b * 8 + sub];
    float e  = __expf(2.f * x);
    float th = 1.f - 2.f / (e + 1.f);             // tanh(x)
    float b2 = th * (0.5f * PI_F) * scale[sub];
    float h0a = b2 + 0.5f * theta[sub];
    float h1a = b2 + 0.5f * theta[8 + sub];
    h2 cs0 = pkrtz(__cosf(h0a), __sinf(h0a));     // layer-0 (c,s)
    h2 csl = pkrtz(__cosf(h1a), __sinf(h1a));     // layer-1 (c,s)

    // ---- broadcast all 8 qubits' packed (c,s), both layers (16 swizzles) ----
    h2 k0 = swzh<BCAST_PAT(0)>(cs0), k1 = swzh<BCAST_PAT(1)>(cs0);
    h2 k2 = swzh<BCAST_PAT(2)>(cs0), k3 = swzh<BCAST_PAT(3)>(cs0);
    h2 k4 = swzh<BCAST_PAT(4)>(cs0), k5 = swzh<BCAST_PAT(5)>(cs0);
    h2 k6 = swzh<BCAST_PAT(6)>(cs0), k7 = swzh<BCAST_PAT(7)>(cs0);
    h2 q0 = swzh<BCAST_PAT(0)>(csl), q1 = swzh<BCAST_PAT(1)>(csl);
    h2 q2 = swzh<BCAST_PAT(2)>(csl), q3 = swzh<BCAST_PAT(3)>(csl);
    h2 q4 = swzh<BCAST_PAT(4)>(csl), q5 = swzh<BCAST_PAT(5)>(csl);
    h2 q6 = swzh<BCAST_PAT(6)>(csl), q7 = swzh<BCAST_PAT(7)>(csl);

    // ================== layout ==================
    // idx = k*32 + sub*4 + h*2 + p   (k: P-register index 0..7; h: half; p: pack elem)
    // idx bits: p=b0, h=b1, sub=b2..4 (lane bits 0-2), k=b5..7 (register index)
    // CZ sign terms: b0b1 (pack*half), b1b2 (h*sub0), b2b3+b3b4 (SL per-lane),
    //                b4b5 (sub2*k0), b5b6+b6b7 (SK per-register: -1 at k=3,6)

    const float SL   = (__popc(sub & (sub >> 1) & 3) & 1) ? -1.f : 1.f;
    const float lam1 = (sub & 1) ? -1.f : 1.f;    // b1b2 factor on h=1
    const float sg4  = (sub & 4) ? -1.f : 1.f;    // b4b5 factor on odd k

    // ---- layer 0 tensor product, CZ#1 folded in f32 (exact) ----
    float G;                                       // qubits 2,3,4 over sub bits
    G  = (sub & 1) ? (float)k2[1] : (float)k2[0];
    G *= (sub & 2) ? (float)k3[1] : (float)k3[0];
    G *= (sub & 4) ? (float)k4[1] : (float)k4[0];
    float Gs = G * SL;

    float f50 = (float)k5[0], f51 = (float)k5[1] * sg4;   // b4b5 folded into f5(1)
    float f60 = (float)k6[0], f61 = (float)k6[1];
    float f70 = (float)k7[0], f71 = (float)k7[1];
    float t0 = Gs * (f50 * f60), t1 = Gs * (f51 * f60);
    float t2 = Gs * (f50 * f61), t3 = Gs * (f51 * f61);
    // W[k] = Gs*H[k]*SK(k)  (SK = -1 at k=3,6)
    const float W[8] = { t0 * f70,  t1 * f70,  t2 * f70, -(t3 * f70),
                         t0 * f71,  t1 * f71, -(t2 * f71), t3 * f71 };

    float m0 = (float)k1[0];           // f1(h=0)
    float m1 = (float)k1[1] * lam1;    // f1(h=1) * b1b2 sign
    float c0f = (float)k0[0], s0f = (float)k0[1];

    h2 P[8][2];
#pragma unroll
    for (int k = 0; k < 8; ++k) {
        float a = W[k] * m0;
        float bb = W[k] * m1;
        P[k][0] = pkrtz(a * c0f, a * s0f);
        P[k][1] = pkrtz(bb * c0f, -(bb * s0f));   // b0b1 sign on (h=1,p=1)
    }

    // ---- layer 1: all 8 gates (commuting) ----
#define PK_KPAIR(KB, cs)  /* qubit 5+log2(KB): butterfly P[k] <-> P[k+KB] */  \
    do {                                                                      \
        h2 c2 = splat_lo(cs), s2 = splat_hi(cs);                              \
        _Pragma("unroll")                                                     \
        for (int bse = 0; bse < 8; bse += 2 * (KB)) {                         \
            _Pragma("unroll")                                                 \
            for (int off = 0; off < (KB); ++off) {                            \
                int ka = bse + off, kb = ka + (KB);                           \
                _Pragma("unroll")                                             \
                for (int h = 0; h < 2; ++h) {                                 \
                    h2 a = P[ka][h], bb = P[kb][h];                           \
                    P[ka][h] = FMA2(c2, a, -(s2 * bb));                       \
                    P[kb][h] = FMA2(c2, bb, s2 * a);                          \
                }                                                             \
            }                                                                 \
        }                                                                     \
    } while (0)

#define PK_CROSS(EXCH, BIT, cs)                                               \
    do {                                                                      \
        h2 c2 = splat_lo(cs), s2 = splat_hi(cs);                              \
        h2 se = (sub & (BIT)) ? s2 : -s2;                                     \
        _Pragma("unroll")                                                     \
        for (int k = 0; k < 8; ++k) {                                         \
            _Pragma("unroll")                                                 \
            for (int h = 0; h < 2; ++h) {                                     \
                h2 t = EXCH(P[k][h]);                                         \
                P[k][h] = FMA2(c2, P[k][h], se * t);                          \
            }                                                                 \
        }                                                                     \
    } while (0)

    {   // qubit 0: within-pack butterfly (R12-proven)
        h2 c2 = splat_lo(q0);
        _Float16 sh = q0[1];
        h2 sm = { (_Float16)(-sh), sh };          // (-s, s)
#pragma unroll
        for (int k = 0; k < 8; ++k) {
            P[k][0] = FMA2(c2, P[k][0], sm * hswap(P[k][0]));
            P[k][1] = FMA2(c2, P[k][1], sm * hswap(P[k][1]));
        }
    }
    {   // qubit 1: butterfly between halves h=0 / h=1
        h2 c2 = splat_lo(q1), s2 = splat_hi(q1);
#pragma unroll
        for (int k = 0; k < 8; ++k) {
            h2 a = P[k][0], bb = P[k][1];
            P[k][0] = FMA2(c2, a, -(s2 * bb));
            P[k][1] = FMA2(c2, bb, s2 * a);
        }
    }
    PK_CROSS(dpph<DPP_XOR1>, 1, q2);   // qubit 2 <-> lane bit 0
    PK_CROSS(dpph<DPP_XOR2>, 2, q3);   // qubit 3 <-> lane bit 1
    PK_CROSS(swzh<SWZ_XOR4>, 4, q4);   // qubit 4 <-> lane bit 2
    PK_KPAIR(1, q5);                   // qubit 5 <-> k bit 0
    PK_KPAIR(2, q6);                   // qubit 6 <-> k bit 1
    PK_KPAIR(4, q7);                   // qubit 7 <-> k bit 2

    // ---- CZ#2: exact +-1 multiplies ----
    // B0(k) = SL*SK(k)*(k odd ? sg4 : 1); h=1 extra lam1 and (1,-1) on pack
#pragma unroll
    for (int k = 0; k < 8; ++k) {
        float skf = (k == 3 || k == 6) ? -1.f : 1.f;
        float B0 = SL * skf * ((k & 1) ? sg4 : 1.f);
        float B1 = B0 * lam1;
        h2 z0 = { (_Float16)B0, (_Float16)B0 };
        h2 z1 = { (_Float16)B1, (_Float16)(-B1) };
        P[k][0] = P[k][0] * z0;
        P[k][1] = P[k][1] * z1;
    }
    // (no normalization: gates orthogonal, ||state|| = 1 within f16 rounding << bf16 tol)

    // ---- direct stores, no LDS: instruction k writes 8 groups x 128B full lines ----
    float* ob = out + (size_t)b * 256 + sub * 4;
#pragma unroll
    for (int k = 0; k < 8; ++k) {
        f32x4 o = { (float)P[k][0][0], (float)P[k][0][1],
                    (float)P[k][1][0], (float)P[k][1][1] };
        __builtin_nontemporal_store(o, reinterpret_cast<f32x4*>(ob + k * 32));
    }
}

extern "C" void kernel_launch(void* const* d_in, const int* in_sizes, int n_in,
                              void* d_out, int out_size, void* d_ws, size_t ws_size,
                              hipStream_t stream) {
    const float* pf    = (const float*)d_in[0];  // [B, 8]
    const float* theta = (const float*)d_in[1];  // [2, 8]
    const float* scale = (const float*)d_in[2];  // [8]
    float* out = (float*)d_out;

    int B = in_sizes[0] / 8;              // 65536
    // 8 batches per wave, 4 waves/block -> 2048 blocks; zero LDS,
    // low VGPR -> up to 8 waves/SIMD for latency hiding
    int grid = B / 8 / 4;
    qenc_kernel<<<grid, 256, 0, stream>>>(pf, theta, scale, out, B);
}

// Round 15
// 17.477 us; speedup vs baseline: 1.3485x; 1.0046x over previous
//
#include <hip/hip_runtime.h>
#include <math.h>

#define PI_F 3.14159265358979323846f

typedef float    f32x4 __attribute__((ext_vector_type(4)));
typedef _Float16 h2    __attribute__((ext_vector_type(2)));

#if __has_builtin(__builtin_elementwise_fma)
#define FMA2(a, b, c) __builtin_elementwise_fma((a), (b), (c))
#else
#define FMA2(a, b, c) ((a) * (b) + (c))
#endif

// v_cvt_pkrtz_f16_f32: packs a->low(elt0), b->high(elt1)
__device__ __forceinline__ h2 pkrtz(float a, float b) {
    return __builtin_bit_cast(h2, __builtin_amdgcn_cvt_pkrtz(a, b));
}

// ---- cross-lane primitives ----
// ds_swizzle BitMode: and=offset[4:0], or=offset[9:5], xor=offset[14:10]
template <int PAT>
__device__ __forceinline__ h2 swzh(h2 x) {
    return __builtin_bit_cast(h2, __builtin_amdgcn_ds_swizzle(__builtin_bit_cast(int, x), PAT));
}
// Broadcast qubit q's (c,s) within each 8-lane group: sub on lane bits 0-2,
// group on lane bits 3,4 (bit 5 auto-preserved): and=0x18, or=q  (R1-proven)
#define BCAST_PAT(q) (((q) << 5) | 0x18)
// Butterfly xor4 within 32-half (ISA-doc pattern)
#define SWZ_XOR4 0x101F

template <int CTRL>
__device__ __forceinline__ h2 dpph(h2 x) {
    int i = __builtin_bit_cast(int, x);
    return __builtin_bit_cast(h2, __builtin_amdgcn_update_dpp(i, i, CTRL, 0xF, 0xF, false));
}
#define DPP_XOR1 0xB1   // quad_perm [1,0,3,2]
#define DPP_XOR2 0x4E   // quad_perm [2,3,0,1]

// boring half-swap: (lo,hi) -> (hi,lo)
__device__ __forceinline__ h2 hswap(h2 a) {
    return __builtin_shufflevector(a, a, 1, 0);
}
__device__ __forceinline__ h2 splat_lo(h2 a) { h2 r = { a[0], a[0] }; return r; }
__device__ __forceinline__ h2 splat_hi(h2 a) { h2 r = { a[1], a[1] }; return r; }

__global__ __launch_bounds__(64) void qenc_kernel(
    const float* __restrict__ pf,     // [B, 8]
    const float* __restrict__ theta,  // [2, 8]
    const float* __restrict__ scale,  // [8]
    float* __restrict__ out,          // [B, 256]
    int B)
{
    const int lane = threadIdx.x & 63;
    const int sub  = lane & 7;        // qubit-owner index AND idx bits 2..4
    const int g    = lane >> 3;       // batch within wave (8 per wave)

    const int bwave = blockIdx.x * 8; // one 8-batch group per 1-wave block
    const int b     = bwave + g;

    // ---- angles: this lane owns qubit `sub` of batch `b`, both layers ----
    float x  = pf[(size_t)b * 8 + sub];
    float e  = __expf(2.f * x);
    float th = 1.f - 2.f / (e + 1.f);             // tanh(x)
    float b2 = th * (0.5f * PI_F) * scale[sub];
    float h0a = b2 + 0.5f * theta[sub];
    float h1a = b2 + 0.5f * theta[8 + sub];
    h2 cs0 = pkrtz(__cosf(h0a), __sinf(h0a));     // layer-0 (c,s)
    h2 csl = pkrtz(__cosf(h1a), __sinf(h1a));     // layer-1 (c,s)

    // ---- broadcast all 8 qubits' packed (c,s), both layers (16 swizzles) ----
    h2 k0 = swzh<BCAST_PAT(0)>(cs0), k1 = swzh<BCAST_PAT(1)>(cs0);
    h2 k2 = swzh<BCAST_PAT(2)>(cs0), k3 = swzh<BCAST_PAT(3)>(cs0);
    h2 k4 = swzh<BCAST_PAT(4)>(cs0), k5 = swzh<BCAST_PAT(5)>(cs0);
    h2 k6 = swzh<BCAST_PAT(6)>(cs0), k7 = swzh<BCAST_PAT(7)>(cs0);
    h2 q0 = swzh<BCAST_PAT(0)>(csl), q1 = swzh<BCAST_PAT(1)>(csl);
    h2 q2 = swzh<BCAST_PAT(2)>(csl), q3 = swzh<BCAST_PAT(3)>(csl);
    h2 q4 = swzh<BCAST_PAT(4)>(csl), q5 = swzh<BCAST_PAT(5)>(csl);
    h2 q6 = swzh<BCAST_PAT(6)>(csl), q7 = swzh<BCAST_PAT(7)>(csl);

    // ================== layout ==================
    // idx = k*32 + sub*4 + h*2 + p   (k: P-register index 0..7; h: half; p: pack elem)
    // idx bits: p=b0, h=b1, sub=b2..4 (lane bits 0-2), k=b5..7 (register index)
    // CZ sign terms: b0b1 (pack*half), b1b2 (h*sub0), b2b3+b3b4 (SL per-lane),
    //                b4b5 (sub2*k0), b5b6+b6b7 (SK per-register: -1 at k=3,6)

    const float SL   = (__popc(sub & (sub >> 1) & 3) & 1) ? -1.f : 1.f;
    const float lam1 = (sub & 1) ? -1.f : 1.f;    // b1b2 factor on h=1
    const float sg4  = (sub & 4) ? -1.f : 1.f;    // b4b5 factor on odd k

    // ---- layer 0 tensor product, CZ#1 folded in f32 (exact) ----
    float G;                                       // qubits 2,3,4 over sub bits
    G  = (sub & 1) ? (float)k2[1] : (float)k2[0];
    G *= (sub & 2) ? (float)k3[1] : (float)k3[0];
    G *= (sub & 4) ? (float)k4[1] : (float)k4[0];
    float Gs = G * SL;

    float f50 = (float)k5[0], f51 = (float)k5[1] * sg4;   // b4b5 folded into f5(1)
    float f60 = (float)k6[0], f61 = (float)k6[1];
    float f70 = (float)k7[0], f71 = (float)k7[1];
    float t0 = Gs * (f50 * f60), t1 = Gs * (f51 * f60);
    float t2 = Gs * (f50 * f61), t3 = Gs * (f51 * f61);
    // W[k] = Gs*H[k]*SK(k)  (SK = -1 at k=3,6)
    const float W[8] = { t0 * f70,  t1 * f70,  t2 * f70, -(t3 * f70),
                         t0 * f71,  t1 * f71, -(t2 * f71), t3 * f71 };

    float m0 = (float)k1[0];           // f1(h=0)
    float m1 = (float)k1[1] * lam1;    // f1(h=1) * b1b2 sign
    float c0f = (float)k0[0], s0f = (float)k0[1];

    h2 P[8][2];
#pragma unroll
    for (int k = 0; k < 8; ++k) {
        float a = W[k] * m0;
        float bb = W[k] * m1;
        P[k][0] = pkrtz(a * c0f, a * s0f);
        P[k][1] = pkrtz(bb * c0f, -(bb * s0f));   // b0b1 sign on (h=1,p=1)
    }

    // ---- layer 1: all 8 gates (commuting) ----
#define PK_KPAIR(KB, cs)  /* qubit 5+log2(KB): butterfly P[k] <-> P[k+KB] */  \
    do {                                                                      \
        h2 c2 = splat_lo(cs), s2 = splat_hi(cs);                              \
        _Pragma("unroll")                                                     \
        for (int bse = 0; bse < 8; bse += 2 * (KB)) {                         \
            _Pragma("unroll")                                                 \
            for (int off = 0; off < (KB); ++off) {                            \
                int ka = bse + off, kb = ka + (KB);                           \
                _Pragma("unroll")                                             \
                for (int h = 0; h < 2; ++h) {                                 \
                    h2 a = P[ka][h], bb = P[kb][h];                           \
                    P[ka][h] = FMA2(c2, a, -(s2 * bb));                       \
                    P[kb][h] = FMA2(c2, bb, s2 * a);                          \
                }                                                             \
            }                                                                 \
        }                                                                     \
    } while (0)

#define PK_CROSS(EXCH, BIT, cs)                                               \
    do {                                                                      \
        h2 c2 = splat_lo(cs), s2 = splat_hi(cs);                              \
        h2 se = (sub & (BIT)) ? s2 : -s2;                                     \
        _Pragma("unroll")                                                     \
        for (int k = 0; k < 8; ++k) {                                         \
            _Pragma("unroll")                                                 \
            for (int h = 0; h < 2; ++h) {                                     \
                h2 t = EXCH(P[k][h]);                                         \
                P[k][h] = FMA2(c2, P[k][h], se * t);                          \
            }                                                                 \
        }                                                                     \
    } while (0)

    {   // qubit 0: within-pack butterfly (R12-proven)
        h2 c2 = splat_lo(q0);
        _Float16 sh = q0[1];
        h2 sm = { (_Float16)(-sh), sh };          // (-s, s)
#pragma unroll
        for (int k = 0; k < 8; ++k) {
            P[k][0] = FMA2(c2, P[k][0], sm * hswap(P[k][0]));
            P[k][1] = FMA2(c2, P[k][1], sm * hswap(P[k][1]));
        }
    }
    {   // qubit 1: butterfly between halves h=0 / h=1
        h2 c2 = splat_lo(q1), s2 = splat_hi(q1);
#pragma unroll
        for (int k = 0; k < 8; ++k) {
            h2 a = P[k][0], bb = P[k][1];
            P[k][0] = FMA2(c2, a, -(s2 * bb));
            P[k][1] = FMA2(c2, bb, s2 * a);
        }
    }
    PK_CROSS(dpph<DPP_XOR1>, 1, q2);   // qubit 2 <-> lane bit 0
    PK_CROSS(dpph<DPP_XOR2>, 2, q3);   // qubit 3 <-> lane bit 1
    PK_CROSS(swzh<SWZ_XOR4>, 4, q4);   // qubit 4 <-> lane bit 2
    PK_KPAIR(1, q5);                   // qubit 5 <-> k bit 0
    PK_KPAIR(2, q6);                   // qubit 6 <-> k bit 1
    PK_KPAIR(4, q7);                   // qubit 7 <-> k bit 2

    // ---- CZ#2: exact +-1 multiplies ----
#pragma unroll
    for (int k = 0; k < 8; ++k) {
        float skf = (k == 3 || k == 6) ? -1.f : 1.f;
        float B0 = SL * skf * ((k & 1) ? sg4 : 1.f);
        float B1 = B0 * lam1;
        h2 z0 = { (_Float16)B0, (_Float16)B0 };
        h2 z1 = { (_Float16)B1, (_Float16)(-B1) };
        P[k][0] = P[k][0] * z0;
        P[k][1] = P[k][1] * z1;
    }
    // (no normalization: gates orthogonal, ||state|| = 1 within f16 rounding << bf16 tol)

    // ---- direct stores, no LDS: instruction k covers 8 groups x 128B full lines ----
    float* ob = out + (size_t)b * 256 + sub * 4;
#pragma unroll
    for (int k = 0; k < 8; ++k) {
        f32x4 o = { (float)P[k][0][0], (float)P[k][0][1],
                    (float)P[k][1][0], (float)P[k][1][1] };
        __builtin_nontemporal_store(o, reinterpret_cast<f32x4*>(ob + k * 32));
    }
}

extern "C" void kernel_launch(void* const* d_in, const int* in_sizes, int n_in,
                              void* d_out, int out_size, void* d_ws, size_t ws_size,
                              hipStream_t stream) {
    const float* pf    = (const float*)d_in[0];  // [B, 8]
    const float* theta = (const float*)d_in[1];  // [2, 8]
    const float* scale = (const float*)d_in[2];  // [8]
    float* out = (float*)d_out;

    int B = in_sizes[0] / 8;              // 65536
    // ONE WAVE PER BLOCK: 8192 blocks of 64 threads. Residency capped by the
    // per-CU workgroup limit (< 32 waves of work per CU) -> multiple
    // generations with continuous refill: gen i+1's compute hides gen i's
    // store drain. No software pipeline, no LDS, no register-reuse pacing.
    int grid = B / 8;
    qenc_kernel<<<grid, 64, 0, stream>>>(pf, theta, scale, out, B);
}